// Round 4
// baseline (582.629 us; speedup 1.0000x reference)
//
#include <hip/hip_runtime.h>
#include <hip/hip_fp16.h>
#include <float.h>
#include <math.h>

#define D 1024
#define BQ 256
#define NMEM 100000
#define TOPK 16
#define NT_SIMS 782              // 128-col tiles covering 100096
#define SIMS_BLOCKS 256
#define CAND 8192                // 256 blocks * 2 halves * 16

typedef __attribute__((ext_vector_type(4))) float f32x4;
typedef __attribute__((ext_vector_type(8))) short s16x8;

__device__ __forceinline__ void mfma16(f32x4& d, s16x8 a, s16x8 b) {
  asm("v_mfma_f32_16x16x32_f16 %0, %1, %2, %0" : "+v"(d) : "v"(a), "v"(b));
}

typedef __attribute__((address_space(3))) unsigned int lds_u32_t;
typedef __attribute__((address_space(1))) const unsigned int gbl_u32_t;
__device__ __forceinline__ void async_copy16(const void* gsrc, void* ldst) {
  __builtin_amdgcn_global_load_lds((gbl_u32_t*)gsrc, (lds_u32_t*)ldst, 16, 0, 0);
}

// ---------------- reductions ----------------

__device__ __forceinline__ float waveReduceSum(float v) {
#pragma unroll
  for (int o = 32; o > 0; o >>= 1) v += __shfl_xor(v, o, 64);
  return v;
}

__device__ __forceinline__ float blockReduceSum(float v, float* sbuf) {
  v = waveReduceSum(v);
  int w = threadIdx.x >> 6;
  if ((threadIdx.x & 63) == 0) sbuf[w] = v;
  __syncthreads();
  float r = sbuf[0] + sbuf[1] + sbuf[2] + sbuf[3];
  __syncthreads();
  return r;
}

// ---------------- prep: split [R][1024] f32 into f16 hi/lo fragment layout --

__global__ __launch_bounds__(256) void prep_kernel(const float* __restrict__ src,
                                                   float* __restrict__ dst,
                                                   int R16) {
  int g = blockIdx.x * 256 + threadIdx.x;
  int l = g & 63;
  int mt = (g >> 6) % R16;
  int kb = (g >> 6) / R16;
  int row = mt * 16 + (l & 15);
  int k0 = kb * 32 + ((l >> 4) << 3);
  const float* s = src + (size_t)row * D + k0;
  float4 v0 = *(const float4*)(s);
  float4 v1 = *(const float4*)(s + 4);
  float xs[8] = {v0.x, v0.y, v0.z, v0.w, v1.x, v1.y, v1.z, v1.w};
  union { float4 f; __half h[8]; } ph, pl;
#pragma unroll
  for (int e = 0; e < 8; ++e) {
    float x = xs[e];
    __half hh = __float2half(x);
    ph.h[e] = hh;
    pl.h[e] = __float2half((x - __half2float(hh)) * 2048.0f);
  }
  char* db = (char*)dst + (size_t)kb * R16 * 2048 + mt * 2048 + l * 16;
  *(float4*)db = ph.f;
  *(float4*)(db + 1024) = pl.f;
}

// ---------------- MFMA projection GEMM (K-chunked, no LDS) -----------------

__global__ __launch_bounds__(256) void mfma_gemm_kernel(
    const float* __restrict__ Afr, const float* __restrict__ Wfr,
    float* __restrict__ part) {
  int t = threadIdx.x;
  int w = t >> 6, l = t & 63;
  int ct = blockIdx.x & 63;
  int kc = blockIdx.x >> 6;
  f32x4 acc1[4], acc2[4];
  f32x4 zz = {0.f, 0.f, 0.f, 0.f};
#pragma unroll
  for (int mi = 0; mi < 4; ++mi) { acc1[mi] = zz; acc2[mi] = zz; }
  const char* ab0 = (const char*)Afr + w * 8192 + l * 16;
  const char* bb0 = (const char*)Wfr + ct * 2048 + l * 16;
#pragma unroll 2
  for (int s = 0; s < 8; ++s) {
    int kb = kc * 8 + s;
    const char* bb = bb0 + (size_t)kb * 131072;
    s16x8 bh = *(const s16x8*)(bb);
    s16x8 bl = *(const s16x8*)(bb + 1024);
    const char* ab = ab0 + (size_t)kb * 32768;
#pragma unroll
    for (int mi = 0; mi < 4; ++mi) {
      s16x8 ah = *(const s16x8*)(ab + mi * 2048);
      s16x8 al = *(const s16x8*)(ab + mi * 2048 + 1024);
      mfma16(acc1[mi], ah, bh);
      mfma16(acc2[mi], ah, bl);
      mfma16(acc2[mi], al, bh);
    }
  }
  float* pb = part + (size_t)kc * 262144 + ct * 16 + (l & 15);
#pragma unroll
  for (int mi = 0; mi < 4; ++mi)
#pragma unroll
    for (int j = 0; j < 4; ++j) {
      int row = w * 64 + mi * 16 + ((l >> 4) << 2) + j;
      pb[(size_t)row * 1024] = acc1[mi][j] + acc2[mi][j] * (1.0f / 2048.0f);
    }
}

// ---------------- reduce partials + bias + LayerNorm + exact GELU ----------

__global__ __launch_bounds__(256) void reduce_ln_gelu_kernel(
    const float* __restrict__ part, const float* __restrict__ bias,
    const float* __restrict__ g, const float* __restrict__ b,
    float* __restrict__ h) {
  __shared__ float sbuf[4];
  int row = blockIdx.x, t = threadIdx.x;
  const float* p = part + (size_t)row * 1024 + t * 4;
  float4 x0 = *(const float4*)(p);
  float4 x1 = *(const float4*)(p + 262144);
  float4 x2 = *(const float4*)(p + 524288);
  float4 x3 = *(const float4*)(p + 786432);
  float4 bb = *(const float4*)(bias + t * 4);
  float vx = x0.x + x1.x + x2.x + x3.x + bb.x;
  float vy = x0.y + x1.y + x2.y + x3.y + bb.y;
  float vz = x0.z + x1.z + x2.z + x3.z + bb.z;
  float vw = x0.w + x1.w + x2.w + x3.w + bb.w;
  float s = blockReduceSum(vx + vy + vz + vw, sbuf);
  float mu = s * (1.0f / D);
  float dx = vx - mu, dy = vy - mu, dz = vz - mu, dw = vw - mu;
  float ss = blockReduceSum(dx * dx + dy * dy + dz * dz + dw * dw, sbuf);
  float rstd = rsqrtf(ss * (1.0f / D) + 1e-5f);
  float4 gg = *(const float4*)(g + t * 4);
  float4 be = *(const float4*)(b + t * 4);
  float y0 = dx * rstd * gg.x + be.x;
  float y1 = dy * rstd * gg.y + be.y;
  float y2 = dz * rstd * gg.z + be.z;
  float y3 = dw * rstd * gg.w + be.w;
  const float c = 0.70710678118654752f;
  y0 = 0.5f * y0 * (1.0f + erff(y0 * c));
  y1 = 0.5f * y1 * (1.0f + erff(y1 * c));
  y2 = 0.5f * y2 * (1.0f + erff(y2 * c));
  y3 = 0.5f * y3 * (1.0f + erff(y3 * c));
  *(float4*)(h + (size_t)row * D + t * 4) = make_float4(y0, y1, y2, y3);
}

// ---------------- reduce partials + bias + L2 normalize --------------------

__global__ __launch_bounds__(256) void reduce_l2norm_kernel(
    const float* __restrict__ part, const float* __restrict__ bias,
    float* __restrict__ r, float* __restrict__ outRef) {
  __shared__ float sbuf[4];
  int row = blockIdx.x, t = threadIdx.x;
  const float* p = part + (size_t)row * 1024 + t * 4;
  float4 x0 = *(const float4*)(p);
  float4 x1 = *(const float4*)(p + 262144);
  float4 x2 = *(const float4*)(p + 524288);
  float4 x3 = *(const float4*)(p + 786432);
  float4 bb = *(const float4*)(bias + t * 4);
  float vx = x0.x + x1.x + x2.x + x3.x + bb.x;
  float vy = x0.y + x1.y + x2.y + x3.y + bb.y;
  float vz = x0.z + x1.z + x2.z + x3.z + bb.z;
  float vw = x0.w + x1.w + x2.w + x3.w + bb.w;
  float ss = blockReduceSum(vx * vx + vy * vy + vz * vz + vw * vw, sbuf);
  float inv = 1.0f / fmaxf(sqrtf(ss), 1e-12f);
  float4 y = make_float4(vx * inv, vy * inv, vz * inv, vw * inv);
  *(float4*)(r + (size_t)row * D + t * 4) = y;
  *(float4*)(outRef + (size_t)row * D + t * 4) = y;
}

__global__ void reset_ctr_kernel(int* c) { *c = 0; }

// ---------------- sims: 8-wave 256x128 tile, work-stealing, topk -----------
// LDS: bufA[3] 0..98304 | bufB[2] 98304..131072 | sP 131072 | sInvF 133120
// S scan region overlays [0, 69632) (256 rows x 68 floats).

#define SIMS_STEP(J, CVA, CVB, ISA, ISB, PA, PBR, PBW, AIW, DOBRAW, DOCONV, DOA, VMN) \
  do {                                                                         \
    if (DOBRAW) {                                                              \
      const float* ba_ = bsrc + ((J) + 3) * 32;                                \
      asm volatile("global_load_dwordx4 %0, %1, off" : "=v"(ISA) : "v"(ba_));  \
      asm volatile("global_load_dwordx4 %0, %1, off offset:16"                 \
                   : "=v"(ISB) : "v"(ba_));                                    \
    }                                                                          \
    if (DOCONV) {                                                              \
      float xs_[8] = {CVA[0], CVA[1], CVA[2], CVA[3],                          \
                      CVB[0], CVB[1], CVB[2], CVB[3]};                         \
      union { s16x8 v; __half h[8]; } ph_, pl_;                                \
      _Pragma("unroll") for (int e = 0; e < 8; ++e) {                          \
        float x_ = xs_[e];                                                     \
        __half hh_ = __float2half(x_);                                         \
        ph_.h[e] = hh_;                                                        \
        pl_.h[e] = __float2half((x_ - __half2float(hh_)) * 2048.0f);           \
        ssq = fmaf(x_, x_, ssq);                                               \
      }                                                                        \
      char* bw_ = smem + 98304 + (PBW)*16384 + bwroff;                         \
      *(s16x8*)bw_ = ph_.v;                                                    \
      *(s16x8*)(bw_ + 1024) = pl_.v;                                           \
    }                                                                          \
    {                                                                          \
      const char* ab_ = smem + (PA)*32768 + (wm * 4) * 2048 + l * 16;          \
      s16x8 ah_[4], al_[4];                                                    \
      _Pragma("unroll") for (int mi = 0; mi < 4; ++mi) {                       \
        ah_[mi] = *(const s16x8*)(ab_ + mi * 2048);                            \
        al_[mi] = *(const s16x8*)(ab_ + mi * 2048 + 1024);                     \
      }                                                                        \
      __builtin_amdgcn_s_setprio(1);                                           \
      _Pragma("unroll") for (int ni = 0; ni < 4; ++ni) {                       \
        const char* bb_ = smem + 98304 + (PBR)*16384 +                         \
                          (wn * 4 + ni) * 2048 + l * 16;                       \
        s16x8 bh_ = *(const s16x8*)bb_;                                        \
        s16x8 bl_ = *(const s16x8*)(bb_ + 1024);                               \
        _Pragma("unroll") for (int mi = 0; mi < 4; ++mi) {                     \
          mfma16(acc1[mi][ni], ah_[mi], bh_);                                  \
          mfma16(acc2[mi][ni], ah_[mi], bl_);                                  \
          mfma16(acc2[mi][ni], al_[mi], bh_);                                  \
        }                                                                      \
      }                                                                        \
      __builtin_amdgcn_s_setprio(0);                                           \
    }                                                                          \
    __builtin_amdgcn_sched_barrier(0);                                         \
    if (DOA) {                                                                 \
      const char* as_ = (const char*)Afrag + (size_t)((J) + 2) * 32768 +       \
                        wq * 1024 + l * 16;                                    \
      char* ad_ = smem + (AIW)*32768 + wq * 1024;                              \
      _Pragma("unroll") for (int u = 0; u < 4; ++u)                            \
        async_copy16(as_ + u * 1024, ad_ + u * 1024);                          \
    }                                                                          \
    asm volatile("s_waitcnt vmcnt(" #VMN ") lgkmcnt(0)\n\ts_barrier"           \
                 ::: "memory");                                                \
    __builtin_amdgcn_sched_barrier(0);                                         \
  } while (0)

__global__ __launch_bounds__(512, 2) void sims_topk_kernel(
    const float* __restrict__ Afrag, const float* __restrict__ mem,
    float* __restrict__ invn, int* __restrict__ ctr,
    float* __restrict__ cand_v, int* __restrict__ cand_i) {
  __shared__ __align__(16) char smem[133632];
  __shared__ int s_tile;
  const int t = threadIdx.x;
  const int w = t >> 6, l = t & 63;
  const int wm = w >> 1, wn = w & 1;
  const int wq = w * 4;

  // B staging role: row n (0..127), k-octet kseg (0..3)
  const int bn = t & 127;
  const int kseg = t >> 7;
  const int bwroff = (bn >> 4) * 2048 + ((bn & 15) + kseg * 16) * 16;

  float* sP = (float*)(smem + 131072);
  float* sInvF = (float*)(smem + 133120);
  float* Sf = (float*)smem;

  float tv[16];
  int ti[16];
#pragma unroll
  for (int s = 0; s < 16; ++s) { tv[s] = -FLT_MAX; ti[s] = 2147483647; }
  float curMin = -FLT_MAX;

  const int myrow = t & 255;      // owned query row
  const int chalf = t >> 8;       // owned 32-col slice within a 64-col chunk

  while (true) {
    if (t == 0) s_tile = atomicAdd(ctr, 1);
    __syncthreads();
    const int tile = s_tile;
    __syncthreads();
    if (tile >= NT_SIMS) break;
    const int n0 = tile * 128;
    const int brow = min(n0 + bn, NMEM - 1);
    const float* bsrc = mem + (size_t)brow * D + kseg * 8;

    f32x4 acc1[4][4], acc2[4][4];
    f32x4 zz = {0.f, 0.f, 0.f, 0.f};
#pragma unroll
    for (int mi = 0; mi < 4; ++mi)
#pragma unroll
      for (int ni = 0; ni < 4; ++ni) { acc1[mi][ni] = zz; acc2[mi][ni] = zz; }
    float ssq = 0.f;
    f32x4 br00, br01, br10, br11, br20, br21;

    // ---- prologue: Braw(0)->s0, Braw(1)->s1, A(0), A(1), Braw(2)->s2
    asm volatile("global_load_dwordx4 %0, %1, off" : "=v"(br00) : "v"(bsrc));
    asm volatile("global_load_dwordx4 %0, %1, off offset:16" : "=v"(br01) : "v"(bsrc));
    {
      const float* b1_ = bsrc + 32;
      asm volatile("global_load_dwordx4 %0, %1, off" : "=v"(br10) : "v"(b1_));
      asm volatile("global_load_dwordx4 %0, %1, off offset:16" : "=v"(br11) : "v"(b1_));
    }
    __builtin_amdgcn_sched_barrier(0);
#pragma unroll
    for (int u = 0; u < 4; ++u)
      async_copy16((const char*)Afrag + wq * 1024 + u * 1024 + l * 16,
                   smem + wq * 1024 + u * 1024);
    __builtin_amdgcn_sched_barrier(0);
#pragma unroll
    for (int u = 0; u < 4; ++u)
      async_copy16((const char*)Afrag + 32768 + wq * 1024 + u * 1024 + l * 16,
                   smem + 32768 + wq * 1024 + u * 1024);
    __builtin_amdgcn_sched_barrier(0);
    {
      const float* b2_ = bsrc + 64;
      asm volatile("global_load_dwordx4 %0, %1, off" : "=v"(br20) : "v"(b2_));
      asm volatile("global_load_dwordx4 %0, %1, off offset:16" : "=v"(br21) : "v"(b2_));
    }
    asm volatile("s_waitcnt vmcnt(6)" ::: "memory");
    __builtin_amdgcn_sched_barrier(0);
    {  // convert Braw(0) -> bufB0
      float xs_[8] = {br00[0], br00[1], br00[2], br00[3],
                      br01[0], br01[1], br01[2], br01[3]};
      union { s16x8 v; __half h[8]; } ph_, pl_;
#pragma unroll
      for (int e = 0; e < 8; ++e) {
        float x_ = xs_[e];
        __half hh_ = __float2half(x_);
        ph_.h[e] = hh_;
        pl_.h[e] = __float2half((x_ - __half2float(hh_)) * 2048.0f);
        ssq = fmaf(x_, x_, ssq);
      }
      char* bw_ = smem + 98304 + bwroff;
      *(s16x8*)bw_ = ph_.v;
      *(s16x8*)(bw_ + 1024) = pl_.v;
    }
    asm volatile("s_waitcnt lgkmcnt(0)\n\ts_barrier" ::: "memory");
    __builtin_amdgcn_sched_barrier(0);

    // ---- steps 0..23 (4 x 6, fully steady)
    for (int it = 0; it < 4; ++it) {
      const int j0 = it * 6;
      SIMS_STEP(j0 + 0, br10, br11, br00, br01, 0, 0, 1, 2, 1, 1, 1, 6);
      SIMS_STEP(j0 + 1, br20, br21, br10, br11, 1, 1, 0, 0, 1, 1, 1, 6);
      SIMS_STEP(j0 + 2, br00, br01, br20, br21, 2, 0, 1, 1, 1, 1, 1, 6);
      SIMS_STEP(j0 + 3, br10, br11, br00, br01, 0, 1, 0, 2, 1, 1, 1, 6);
      SIMS_STEP(j0 + 4, br20, br21, br10, br11, 1, 0, 1, 0, 1, 1, 1, 6);
      SIMS_STEP(j0 + 5, br00, br01, br20, br21, 2, 1, 0, 1, 1, 1, 1, 6);
    }
    // ---- steps 24..31 (tail)
    SIMS_STEP(24, br10, br11, br00, br01, 0, 0, 1, 2, 1, 1, 1, 6);
    SIMS_STEP(25, br20, br21, br10, br11, 1, 1, 0, 0, 1, 1, 1, 6);
    SIMS_STEP(26, br00, br01, br20, br21, 2, 0, 1, 1, 1, 1, 1, 6);
    SIMS_STEP(27, br10, br11, br00, br01, 0, 1, 0, 2, 1, 1, 1, 6);
    SIMS_STEP(28, br20, br21, br10, br11, 1, 0, 1, 0, 1, 1, 1, 6);
    SIMS_STEP(29, br00, br01, br20, br21, 2, 1, 0, 1, 0, 1, 1, 4);
    SIMS_STEP(30, br10, br11, br00, br01, 0, 0, 1, 2, 0, 1, 0, 0);
    SIMS_STEP(31, br20, br21, br10, br11, 1, 1, 0, 0, 0, 0, 0, 0);

    // ---- norms + scan/topk
    sP[kseg * 128 + bn] = ssq;
    if (wn == 0) {  // dump col-half 0
#pragma unroll
      for (int mi = 0; mi < 4; ++mi)
#pragma unroll
        for (int ni = 0; ni < 4; ++ni)
#pragma unroll
          for (int jj = 0; jj < 4; ++jj) {
            int row = wm * 64 + mi * 16 + ((l >> 4) << 2) + jj;
            Sf[row * 68 + ni * 16 + (l & 15)] =
                acc1[mi][ni][jj] + acc2[mi][ni][jj] * (1.0f / 2048.0f);
          }
    }
    __syncthreads();
    if (t < 128) {
      float s4 = sP[t] + sP[128 + t] + sP[256 + t] + sP[384 + t];
      float inv = 1.0f / fmaxf(sqrtf(s4), 1e-12f);
      sInvF[t] = inv;
      if (n0 + t < NMEM) invn[n0 + t] = inv;
    }
    __syncthreads();
#pragma unroll
    for (int half = 0; half < 2; ++half) {
      if (half == 1) {
        __syncthreads();
        if (wn == 1) {
#pragma unroll
          for (int mi = 0; mi < 4; ++mi)
#pragma unroll
            for (int ni = 0; ni < 4; ++ni)
#pragma unroll
              for (int jj = 0; jj < 4; ++jj) {
                int row = wm * 64 + mi * 16 + ((l >> 4) << 2) + jj;
                Sf[row * 68 + ni * 16 + (l & 15)] =
                    acc1[mi][ni][jj] + acc2[mi][ni][jj] * (1.0f / 2048.0f);
              }
        }
        __syncthreads();
      }
      const float* Srow = Sf + myrow * 68 + chalf * 32;
      const float* sIv = sInvF + half * 64 + chalf * 32;
      const int nb = n0 + half * 64 + chalf * 32;
#pragma unroll
      for (int c4 = 0; c4 < 32; c4 += 4) {
        float4 sv = *(const float4*)(Srow + c4);
        float vv[4] = {sv.x, sv.y, sv.z, sv.w};
#pragma unroll
        for (int e = 0; e < 4; ++e) {
          int n = nb + c4 + e;
          float v = vv[e] * sIv[c4 + e];
          if (n < NMEM && v > curMin) {
            int ms = 0;
            float mv = tv[0];
#pragma unroll
            for (int s = 1; s < 16; ++s)
              if (tv[s] < mv) { mv = tv[s]; ms = s; }
#pragma unroll
            for (int s = 0; s < 16; ++s)
              if (s == ms) { tv[s] = v; ti[s] = n; }
            curMin = tv[0];
#pragma unroll
            for (int s = 1; s < 16; ++s) curMin = fminf(curMin, tv[s]);
          }
        }
      }
    }
    __syncthreads();  // scan reads done before next tile's staging
  }

  float* cv = cand_v + (size_t)blockIdx.x * 8192 + (size_t)chalf * 4096 +
              (size_t)myrow * 16;
  int* ci = cand_i + (size_t)blockIdx.x * 8192 + (size_t)chalf * 4096 +
            (size_t)myrow * 16;
#pragma unroll
  for (int s = 0; s < 16; ++s) { cv[s] = tv[s]; ci[s] = ti[s]; }
}

// ---------------- merge per-thread top-16s (tie-aware, stable) -------------

__global__ __launch_bounds__(256) void topk_merge_kernel(
    const float* __restrict__ cand_v, const int* __restrict__ cand_i,
    float* __restrict__ out_vals, float* __restrict__ out_idx) {
  __shared__ float rv[256];
  __shared__ int ri[256];
  int b = blockIdx.x, t = threadIdx.x;
  float lastV = FLT_MAX;
  int lastI = -1;
  for (int pass = 0; pass < TOPK; ++pass) {
    float bv = -FLT_MAX;
    int bi = 2147483647;
    for (int p = t; p < CAND; p += 256) {
      size_t a = (size_t)(p >> 5) * 8192 + (size_t)((p >> 4) & 1) * 4096 +
                 (size_t)b * 16 + (p & 15);
      float v = cand_v[a];
      int idx = cand_i[a];
      bool qual = (v < lastV) || (v == lastV && idx > lastI);
      bool better = (v > bv) || (v == bv && idx < bi);
      if (qual && better) { bv = v; bi = idx; }
    }
    rv[t] = bv; ri[t] = bi;
    __syncthreads();
    for (int off = 128; off > 0; off >>= 1) {
      if (t < off) {
        float v2 = rv[t + off];
        int i2 = ri[t + off];
        if (v2 > rv[t] || (v2 == rv[t] && i2 < ri[t])) { rv[t] = v2; ri[t] = i2; }
      }
      __syncthreads();
    }
    lastV = rv[0];
    lastI = ri[0];
    if (t == 0) {
      out_vals[b * TOPK + pass] = lastV;
      out_idx[b * TOPK + pass] = (float)lastI;
    }
    __syncthreads();
  }
}

// ---------------- gather retrieved = mem_n[topk_idx] -----------------------

__global__ __launch_bounds__(256) void gather_kernel(
    const float* __restrict__ out_idx, const float* __restrict__ mem,
    const float* __restrict__ invn, float* __restrict__ out_retr) {
  int p = blockIdx.x;
  int idx = (int)out_idx[p];
  float inv = invn[idx];
  int c = threadIdx.x * 4;
  float4 v = *(const float4*)(mem + (size_t)idx * D + c);
  v.x *= inv; v.y *= inv; v.z *= inv; v.w *= inv;
  *(float4*)(out_retr + (size_t)p * D + c) = v;
}

// ---------------- launch ---------------------------------------------------

extern "C" void kernel_launch(void* const* d_in, const int* in_sizes, int n_in,
                              void* d_out, int out_size, void* d_ws, size_t ws_size,
                              hipStream_t stream) {
  const float* query = (const float*)d_in[0];
  const float* W1 = (const float*)d_in[1];
  const float* b1 = (const float*)d_in[2];
  const float* ln_g = (const float*)d_in[3];
  const float* ln_b = (const float*)d_in[4];
  const float* W2 = (const float*)d_in[5];
  const float* b2 = (const float*)d_in[6];
  const float* mem = (const float*)d_in[7];

  float* out = (float*)d_out;
  float* out_refined = out;                    // 262144
  float* out_vals = out + 262144;              // 4096
  float* out_idx = out + 262144 + 4096;        // 4096
  float* out_retr = out + 262144 + 8192;       // 256*16*1024

  float* wsp = (float*)d_ws;
  float* h = wsp;                              // 262144
  float* r = wsp + 262144;                     // 262144
  float* invn = wsp + 524288;                  // 100352
  float* Qf = wsp + 624640;                    // 262144 (also Hf)
  float* Af = wsp + 886784;                    // 262144
  float* W1f = wsp + 1148928;                  // 1048576
  float* W2f = wsp + 2197504;                  // 1048576
  float* part = wsp + 3246080;                 // 1048576
  float* cand_v = wsp + 4294656;               // 2097152
  int* cand_i = (int*)(wsp + 6391808);         // 2097152
  int* ctr = (int*)(wsp + 8488960);            // 1

  prep_kernel<<<128, 256, 0, stream>>>(query, Qf, 16);
  prep_kernel<<<512, 256, 0, stream>>>(W1, W1f, 64);
  prep_kernel<<<512, 256, 0, stream>>>(W2, W2f, 64);
  mfma_gemm_kernel<<<256, 256, 0, stream>>>(Qf, W1f, part);
  reduce_ln_gelu_kernel<<<256, 256, 0, stream>>>(part, b1, ln_g, ln_b, h);
  prep_kernel<<<128, 256, 0, stream>>>(h, Qf, 16);
  mfma_gemm_kernel<<<256, 256, 0, stream>>>(Qf, W2f, part);
  reduce_l2norm_kernel<<<256, 256, 0, stream>>>(part, b2, r, out_refined);
  prep_kernel<<<128, 256, 0, stream>>>(r, Af, 16);
  reset_ctr_kernel<<<1, 1, 0, stream>>>(ctr);
  sims_topk_kernel<<<SIMS_BLOCKS, 512, 0, stream>>>(Af, mem, invn, ctr,
                                                    cand_v, cand_i);
  topk_merge_kernel<<<BQ, 256, 0, stream>>>(cand_v, cand_i, out_vals, out_idx);
  gather_kernel<<<BQ * TOPK, 256, 0, stream>>>(out_idx, mem, invn, out_retr);
}

// Round 5
// 419.727 us; speedup vs baseline: 1.3881x; 1.3881x over previous
//
#include <hip/hip_runtime.h>
#include <float.h>
#include <math.h>

#define D 1024
#define BQ 256
#define NMEM 100000
#define TOPK 16
#define NT_TOT 1563   // 64-col tiles covering 100032 >= 100000

typedef __attribute__((ext_vector_type(4))) float f32x4;
typedef __attribute__((ext_vector_type(8))) short s16x8;

__device__ __forceinline__ void mfma16(f32x4& d, s16x8 a, s16x8 b) {
  asm("v_mfma_f32_16x16x32_bf16 %0, %1, %2, %0" : "+v"(d) : "v"(a), "v"(b));
}

typedef __attribute__((address_space(3))) unsigned int lds_u32_t;
typedef __attribute__((address_space(1))) const unsigned int gbl_u32_t;
__device__ __forceinline__ void async_copy16(const void* gsrc, void* ldst) {
  __builtin_amdgcn_global_load_lds((gbl_u32_t*)gsrc, (lds_u32_t*)ldst, 16, 0, 0);
}

#define GLOAD(dst, addr) \
  asm volatile("global_load_dwordx4 %0, %1, off" : "=v"(dst) : "v"(addr))

__device__ __forceinline__ unsigned short bf16rtne(float x) {
  unsigned u = __float_as_uint(x);
  unsigned r = u + 0x7fffu + ((u >> 16) & 1u);
  return (unsigned short)(r >> 16);
}

__device__ __forceinline__ void cvt8(f32x4 a, f32x4 b, s16x8* hi, s16x8* lo,
                                     float* ssq) {
  float xs[8] = {a[0], a[1], a[2], a[3], b[0], b[1], b[2], b[3]};
  union { s16x8 v; unsigned short u[8]; } H, L;
#pragma unroll
  for (int e = 0; e < 8; ++e) {
    float x = xs[e];
    unsigned short h = bf16rtne(x);
    float hf = __uint_as_float(((unsigned)h) << 16);
    H.u[e] = (short)h;
    L.u[e] = (short)bf16rtne(x - hf);
    *ssq = fmaf(x, x, *ssq);
  }
  *hi = H.v;
  *lo = L.v;
}

// ---------------- reductions ----------------

__device__ __forceinline__ float waveReduceSum(float v) {
#pragma unroll
  for (int o = 32; o > 0; o >>= 1) v += __shfl_xor(v, o, 64);
  return v;
}

__device__ __forceinline__ float blockReduceSum(float v, float* sbuf) {
  v = waveReduceSum(v);
  int w = threadIdx.x >> 6;
  if ((threadIdx.x & 63) == 0) sbuf[w] = v;
  __syncthreads();
  float r = sbuf[0] + sbuf[1] + sbuf[2] + sbuf[3];
  __syncthreads();
  return r;
}

// ---------------- prep: split [R][1024] f32 into bf16 hi/lo frag layout ----

__global__ __launch_bounds__(256) void prep_bf16_kernel(
    const float* __restrict__ src, float* __restrict__ dst, int R16) {
  int g = blockIdx.x * 256 + threadIdx.x;
  int l = g & 63;
  int mt = (g >> 6) % R16;
  int kb = (g >> 6) / R16;
  int row = mt * 16 + (l & 15);
  int k0 = kb * 32 + ((l >> 4) << 3);
  const float* s = src + (size_t)row * D + k0;
  float4 v0 = *(const float4*)s;
  float4 v1 = *(const float4*)(s + 4);
  float xs[8] = {v0.x, v0.y, v0.z, v0.w, v1.x, v1.y, v1.z, v1.w};
  union { uint4 q; unsigned short u[8]; } H, L;
#pragma unroll
  for (int e = 0; e < 8; ++e) {
    float x = xs[e];
    unsigned short h = bf16rtne(x);
    float hf = __uint_as_float(((unsigned)h) << 16);
    H.u[e] = h;
    L.u[e] = bf16rtne(x - hf);
  }
  char* db = (char*)dst + (size_t)kb * (R16 * 2048) + mt * 2048 + l * 16;
  *(uint4*)db = H.q;
  *(uint4*)(db + 1024) = L.q;
}

// ---------------- MFMA projection GEMM (K-chunked, bf16 single-acc) --------

__global__ __launch_bounds__(256) void mfma_gemm_kernel(
    const float* __restrict__ Afr, const float* __restrict__ Wfr,
    float* __restrict__ part) {
  int t = threadIdx.x;
  int w = t >> 6, l = t & 63;
  int ct = blockIdx.x & 63;
  int kc = blockIdx.x >> 6;
  f32x4 acc[4];
  f32x4 zz = {0.f, 0.f, 0.f, 0.f};
#pragma unroll
  for (int mi = 0; mi < 4; ++mi) acc[mi] = zz;
  const char* ab0 = (const char*)Afr + w * 8192 + l * 16;
  const char* bb0 = (const char*)Wfr + ct * 2048 + l * 16;
#pragma unroll 2
  for (int s = 0; s < 8; ++s) {
    int kb = kc * 8 + s;
    const char* bb = bb0 + (size_t)kb * 131072;
    s16x8 bh = *(const s16x8*)(bb);
    s16x8 bl = *(const s16x8*)(bb + 1024);
    const char* ab = ab0 + (size_t)kb * 32768;
#pragma unroll
    for (int mi = 0; mi < 4; ++mi) {
      s16x8 ah = *(const s16x8*)(ab + mi * 2048);
      s16x8 al = *(const s16x8*)(ab + mi * 2048 + 1024);
      mfma16(acc[mi], ah, bh);
      mfma16(acc[mi], ah, bl);
      mfma16(acc[mi], al, bh);
    }
  }
  float* pb = part + (size_t)kc * 262144 + ct * 16 + (l & 15);
#pragma unroll
  for (int mi = 0; mi < 4; ++mi)
#pragma unroll
    for (int j = 0; j < 4; ++j) {
      int row = w * 64 + mi * 16 + ((l >> 4) << 2) + j;
      pb[(size_t)row * 1024] = acc[mi][j];
    }
}

// ------- reduce partials + bias + LayerNorm + GELU -> Hf bf16 frags --------

__global__ __launch_bounds__(256) void reduce_ln_gelu_kernel(
    const float* __restrict__ part, const float* __restrict__ bias,
    const float* __restrict__ g, const float* __restrict__ b,
    float* __restrict__ Hf) {
  __shared__ float sbuf[4];
  int row = blockIdx.x, t = threadIdx.x;
  const float* p = part + (size_t)row * 1024 + t * 4;
  float4 x0 = *(const float4*)(p);
  float4 x1 = *(const float4*)(p + 262144);
  float4 x2 = *(const float4*)(p + 524288);
  float4 x3 = *(const float4*)(p + 786432);
  float4 bb = *(const float4*)(bias + t * 4);
  float vx = x0.x + x1.x + x2.x + x3.x + bb.x;
  float vy = x0.y + x1.y + x2.y + x3.y + bb.y;
  float vz = x0.z + x1.z + x2.z + x3.z + bb.z;
  float vw = x0.w + x1.w + x2.w + x3.w + bb.w;
  float s = blockReduceSum(vx + vy + vz + vw, sbuf);
  float mu = s * (1.0f / D);
  float dx = vx - mu, dy = vy - mu, dz = vz - mu, dw = vw - mu;
  float ss = blockReduceSum(dx * dx + dy * dy + dz * dz + dw * dw, sbuf);
  float rstd = rsqrtf(ss * (1.0f / D) + 1e-5f);
  float4 gg = *(const float4*)(g + t * 4);
  float4 be = *(const float4*)(b + t * 4);
  float y[4];
  y[0] = dx * rstd * gg.x + be.x;
  y[1] = dy * rstd * gg.y + be.y;
  y[2] = dz * rstd * gg.z + be.z;
  y[3] = dw * rstd * gg.w + be.w;
  const float c = 0.70710678118654752f;
  union { uint2 q; unsigned short u[4]; } H, L;
#pragma unroll
  for (int e = 0; e < 4; ++e) {
    float ye = 0.5f * y[e] * (1.0f + erff(y[e] * c));
    unsigned short h = bf16rtne(ye);
    float hf = __uint_as_float(((unsigned)h) << 16);
    H.u[e] = h;
    L.u[e] = bf16rtne(ye - hf);
  }
  int kb = t >> 3, oct = (t >> 1) & 3;
  char* db = (char*)Hf + (size_t)kb * 32768 + (row >> 4) * 2048 +
             ((row & 15) + oct * 16) * 16 + (t & 1) * 8;
  *(uint2*)db = H.q;
  *(uint2*)(db + 1024) = L.q;
}

// ------- reduce partials + bias + L2 norm -> out_refined + Af bf16 frags ---

__global__ __launch_bounds__(256) void reduce_l2norm_kernel(
    const float* __restrict__ part, const float* __restrict__ bias,
    float* __restrict__ outRef, float* __restrict__ Af) {
  __shared__ float sbuf[4];
  int row = blockIdx.x, t = threadIdx.x;
  const float* p = part + (size_t)row * 1024 + t * 4;
  float4 x0 = *(const float4*)(p);
  float4 x1 = *(const float4*)(p + 262144);
  float4 x2 = *(const float4*)(p + 524288);
  float4 x3 = *(const float4*)(p + 786432);
  float4 bb = *(const float4*)(bias + t * 4);
  float vx = x0.x + x1.x + x2.x + x3.x + bb.x;
  float vy = x0.y + x1.y + x2.y + x3.y + bb.y;
  float vz = x0.z + x1.z + x2.z + x3.z + bb.z;
  float vw = x0.w + x1.w + x2.w + x3.w + bb.w;
  float ss = blockReduceSum(vx * vx + vy * vy + vz * vz + vw * vw, sbuf);
  float inv = 1.0f / fmaxf(sqrtf(ss), 1e-12f);
  float y[4] = {vx * inv, vy * inv, vz * inv, vw * inv};
  *(float4*)(outRef + (size_t)row * D + t * 4) =
      make_float4(y[0], y[1], y[2], y[3]);
  union { uint2 q; unsigned short u[4]; } H, L;
#pragma unroll
  for (int e = 0; e < 4; ++e) {
    unsigned short h = bf16rtne(y[e]);
    float hf = __uint_as_float(((unsigned)h) << 16);
    H.u[e] = h;
    L.u[e] = bf16rtne(y[e] - hf);
  }
  int kb = t >> 3, oct = (t >> 1) & 3;
  char* db = (char*)Af + (size_t)kb * 32768 + (row >> 4) * 2048 +
             ((row & 15) + oct * 16) * 16 + (t & 1) * 8;
  *(uint2*)db = H.q;
  *(uint2*)(db + 1024) = L.q;
}

__global__ void zero_ctrs_kernel(int* c) { c[threadIdx.x] = 0; }

// ---------------- sims GEMM: 256x64 tiles, work-steal, scaled store --------
// LDS: A 32768 | B dbuf 2x8192 | sP 1024 @49152 | sInv 256 @50176 = 50432
// Per K-step: [frag reads][bar1][A(j+1) async][Braw(j+2)][vmcnt; conv B(j+1)
//  -> buf[(j+1)&1]][48 MFMA][vmcnt(2) lgkm(0) bar2]

#define SBODY(J, CV0, CV1, NV0, NV1, PBR, PBW, DO_A, DO_PF, DO_CONV, VMC,      \
              DO_BAR2, VME)                                                    \
  do {                                                                         \
    _Pragma("unroll") for (int mi = 0; mi < 4; ++mi) {                         \
      const char* ab_ = smem + (w4 + mi) * 2048 + l * 16;                      \
      ah[mi] = *(const s16x8*)ab_;                                             \
      al[mi] = *(const s16x8*)(ab_ + 1024);                                    \
    }                                                                          \
    asm volatile("s_waitcnt lgkmcnt(0)\n\ts_barrier" ::: "memory");            \
    if (DO_A) {                                                                \
      const char* as_ =                                                        \
          afbytes + (size_t)((J) + 1) * 32768 + w * 8192 + l * 16;             \
      char* ad_ = smem + w * 8192;                                             \
      _Pragma("unroll") for (int u = 0; u < 8; ++u)                            \
        async_copy16(as_ + u * 1024, ad_ + u * 1024);                          \
    }                                                                          \
    if (DO_PF) {                                                               \
      const float* p_ = bsrc + ((J) + 2) * 32;                                 \
      GLOAD(NV0, p_);                                                          \
      GLOAD(NV1, p_ + 4);                                                      \
    }                                                                          \
    if (DO_CONV) {                                                             \
      asm volatile("s_waitcnt vmcnt(" #VMC ")" ::: "memory");                  \
      __builtin_amdgcn_sched_barrier(0);                                       \
      s16x8 bhn_, bln_;                                                        \
      cvt8(CV0, CV1, &bhn_, &bln_, &ssq);                                      \
      *(s16x8*)(smem + 32768 + (PBW)*8192 + bwoff) = bhn_;                     \
      *(s16x8*)(smem + 32768 + (PBW)*8192 + bwoff + 1024) = bln_;              \
    }                                                                          \
    __builtin_amdgcn_s_setprio(1);                                             \
    _Pragma("unroll") for (int ni = 0; ni < 4; ++ni) {                         \
      const char* bb_ = smem + 32768 + (PBR)*8192 + ni * 2048 + l * 16;        \
      s16x8 bh_ = *(const s16x8*)bb_;                                          \
      s16x8 bl_ = *(const s16x8*)(bb_ + 1024);                                 \
      _Pragma("unroll") for (int mi = 0; mi < 4; ++mi) {                       \
        mfma16(acc[mi][ni], ah[mi], bh_);                                      \
        mfma16(acc[mi][ni], ah[mi], bl_);                                      \
        mfma16(acc[mi][ni], al[mi], bh_);                                      \
      }                                                                        \
    }                                                                          \
    __builtin_amdgcn_s_setprio(0);                                             \
    if (DO_BAR2)                                                               \
      asm volatile("s_waitcnt vmcnt(" #VME ") lgkmcnt(0)\n\ts_barrier" :::     \
                       "memory");                                              \
  } while (0)

__global__ __launch_bounds__(256, 3) void sims_gemm_kernel(
    const float* __restrict__ Afrag, const float* __restrict__ mem,
    float* __restrict__ invn, int* __restrict__ ctr,
    float* __restrict__ simsbuf, int ntiles, int chunk_n0, int stride_cols) {
  __shared__ __align__(16) char smem[50432];
  __shared__ int s_tile;
  const int t = threadIdx.x;
  const int w = t >> 6, l = t & 63;
  const int w4 = w * 4;
  const int brow_loc = t >> 2;
  const int kseg = t & 3;
  const int bwoff = (brow_loc >> 4) * 2048 + ((brow_loc & 15) + kseg * 16) * 16;
  const char* afbytes = (const char*)Afrag;
  float* sPf = (float*)(smem + 49152);
  float* sInvF = (float*)(smem + 50176);

  while (true) {
    if (t == 0) s_tile = atomicAdd(ctr, 1);
    __syncthreads();
    const int unit = s_tile;
    if (unit >= ntiles) break;
    const int n0 = chunk_n0 + unit * 64;
    const int brow = min(n0 + brow_loc, NMEM - 1);
    const float* bsrc = mem + (size_t)brow * D + kseg * 8;

    f32x4 acc[4][4];
    f32x4 zz = {0.f, 0.f, 0.f, 0.f};
#pragma unroll
    for (int mi = 0; mi < 4; ++mi)
#pragma unroll
      for (int ni = 0; ni < 4; ++ni) acc[mi][ni] = zz;
    float ssq = 0.f;
    s16x8 ah[4], al[4];
    f32x4 br_a0, br_a1, br_b0, br_b1;

    // ---- prologue: Braw(0)->a, Braw(1)->b, A(0); conv(0)->buf0
    GLOAD(br_a0, bsrc);
    GLOAD(br_a1, bsrc + 4);
    {
      const float* p1 = bsrc + 32;
      GLOAD(br_b0, p1);
      GLOAD(br_b1, p1 + 4);
    }
    {
      const char* as_ = afbytes + w * 8192 + l * 16;
      char* ad_ = smem + w * 8192;
#pragma unroll
      for (int u = 0; u < 8; ++u) async_copy16(as_ + u * 1024, ad_ + u * 1024);
    }
    asm volatile("s_waitcnt vmcnt(10)" ::: "memory");
    __builtin_amdgcn_sched_barrier(0);
    {
      s16x8 bh0, bl0;
      cvt8(br_a0, br_a1, &bh0, &bl0, &ssq);
      *(s16x8*)(smem + 32768 + bwoff) = bh0;
      *(s16x8*)(smem + 32768 + bwoff + 1024) = bl0;
    }
    asm volatile("s_waitcnt vmcnt(2) lgkmcnt(0)\n\ts_barrier" ::: "memory");

    // ---- steady bodies 0..29
#pragma unroll 1
    for (int j = 0; j < 30; j += 2) {
      SBODY(j, br_b0, br_b1, br_a0, br_a1, 0, 1, 1, 1, 1, 10, 1, 2);
      SBODY(j + 1, br_a0, br_a1, br_b0, br_b1, 1, 0, 1, 1, 1, 10, 1, 2);
    }
    // ---- body 30: conv(31), A(31), no prefetch
    SBODY(30, br_b0, br_b1, br_a0, br_a1, 0, 1, 1, 0, 1, 8, 1, 0);
    // ---- body 31: compute only
    SBODY(31, br_a0, br_a1, br_b0, br_b1, 1, 0, 0, 0, 0, 0, 0, 0);

    // ---- epilogue: col norms + scaled store
    __syncthreads();
    sPf[t] = ssq;
    __syncthreads();
    if (t < 64) {
      float s = sPf[t * 4] + sPf[t * 4 + 1] + sPf[t * 4 + 2] + sPf[t * 4 + 3];
      float inv = 1.0f / fmaxf(sqrtf(s), 1e-12f);
      sInvF[t] = inv;
      int col = n0 + t;
      if (col < NMEM) invn[col] = inv;
    }
    __syncthreads();
    float siv[4];
#pragma unroll
    for (int ni = 0; ni < 4; ++ni) siv[ni] = sInvF[ni * 16 + (l & 15)];
    float* srow = simsbuf + (size_t)(unit * 64);
#pragma unroll
    for (int mi = 0; mi < 4; ++mi)
#pragma unroll
      for (int jj = 0; jj < 4; ++jj) {
        int row = w * 64 + mi * 16 + ((l >> 4) << 2) + jj;
        float* rp = srow + (size_t)row * stride_cols;
#pragma unroll
        for (int ni = 0; ni < 4; ++ni)
          rp[ni * 16 + (l & 15)] = acc[mi][ni][jj] * siv[ni];
      }
  }
}

// ---------------- per-chunk top-16 scan over scaled sims -------------------

__global__ __launch_bounds__(512) void topk_chunk_kernel(
    const float* __restrict__ simsbuf, int stride_cols, int chunk_n0,
    int nvalid, float* __restrict__ cv, int* __restrict__ ci) {
  __shared__ float wvv[8];
  __shared__ int wii[8];
  __shared__ float sbv;
  __shared__ int sbi;
  int row = blockIdx.x, t = threadIdx.x;
  const float* S = simsbuf + (size_t)row * stride_cols;
  float tv[16];
  int ti[16];
#pragma unroll
  for (int s = 0; s < 16; ++s) { tv[s] = -FLT_MAX; ti[s] = 2147483647; }
  float curMin = -FLT_MAX;
  for (int c0 = t * 4; c0 < nvalid; c0 += 2048) {
    float vv[4] = {-FLT_MAX, -FLT_MAX, -FLT_MAX, -FLT_MAX};
    if (c0 + 4 <= nvalid) {
      float4 v = *(const float4*)(S + c0);
      vv[0] = v.x; vv[1] = v.y; vv[2] = v.z; vv[3] = v.w;
    } else {
#pragma unroll
      for (int e = 0; e < 4; ++e)
        if (c0 + e < nvalid) vv[e] = S[c0 + e];
    }
#pragma unroll
    for (int e = 0; e < 4; ++e) {
      float v = vv[e];
      if (v > curMin) {
        int n = chunk_n0 + c0 + e;
        int ms = 0;
        float mv = tv[0];
#pragma unroll
        for (int s = 1; s < 16; ++s)
          if (tv[s] < mv) { mv = tv[s]; ms = s; }
#pragma unroll
        for (int s = 0; s < 16; ++s)
          if (s == ms) { tv[s] = v; ti[s] = n; }
        curMin = tv[0];
#pragma unroll
        for (int s = 1; s < 16; ++s) curMin = fminf(curMin, tv[s]);
      }
    }
  }
  // merge 512 x top16 -> chunk top16 (tie-aware)
  float lastV = FLT_MAX;
  int lastI = -1;
  for (int pass = 0; pass < TOPK; ++pass) {
    float bv = -FLT_MAX;
    int bi = 2147483647;
#pragma unroll
    for (int s = 0; s < 16; ++s) {
      float v = tv[s];
      int idx = ti[s];
      bool qual = (v < lastV) || (v == lastV && idx > lastI);
      bool bet = (v > bv) || (v == bv && idx < bi);
      if (qual && bet) { bv = v; bi = idx; }
    }
#pragma unroll
    for (int o = 32; o > 0; o >>= 1) {
      float v2 = __shfl_xor(bv, o, 64);
      int i2 = __shfl_xor(bi, o, 64);
      if (v2 > bv || (v2 == bv && i2 < bi)) { bv = v2; bi = i2; }
    }
    if ((t & 63) == 0) { wvv[t >> 6] = bv; wii[t >> 6] = bi; }
    __syncthreads();
    if (t == 0) {
      float fv = wvv[0];
      int fi = wii[0];
#pragma unroll
      for (int u = 1; u < 8; ++u) {
        if (wvv[u] > fv || (wvv[u] == fv && wii[u] < fi)) {
          fv = wvv[u];
          fi = wii[u];
        }
      }
      sbv = fv;
      sbi = fi;
      cv[row * TOPK + pass] = fv;
      ci[row * TOPK + pass] = fi;
    }
    __syncthreads();
    lastV = sbv;
    lastI = sbi;
  }
}

// ---------------- final merge across chunks --------------------------------

__global__ __launch_bounds__(64) void final_merge_kernel(
    const float* __restrict__ cand_v, const int* __restrict__ cand_i,
    int nchunk, float* __restrict__ out_vals, float* __restrict__ out_idx) {
  int row = blockIdx.x, l = threadIdx.x;
  int nc = nchunk * TOPK;
  float mv[8];
  int mi_[8];
#pragma unroll
  for (int u = 0; u < 8; ++u) {
    int p = l + u * 64;
    if (p < nc) {
      int ch = p >> 4;
      mv[u] = cand_v[ch * 4096 + row * TOPK + (p & 15)];
      mi_[u] = cand_i[ch * 4096 + row * TOPK + (p & 15)];
    } else {
      mv[u] = -FLT_MAX;
      mi_[u] = 2147483647;
    }
  }
  float lastV = FLT_MAX;
  int lastI = -1;
  for (int pass = 0; pass < TOPK; ++pass) {
    float bv = -FLT_MAX;
    int bi = 2147483647;
#pragma unroll
    for (int u = 0; u < 8; ++u) {
      bool qual = (mv[u] < lastV) || (mv[u] == lastV && mi_[u] > lastI);
      bool bet = (mv[u] > bv) || (mv[u] == bv && mi_[u] < bi);
      if (qual && bet) { bv = mv[u]; bi = mi_[u]; }
    }
#pragma unroll
    for (int o = 32; o > 0; o >>= 1) {
      float v2 = __shfl_xor(bv, o, 64);
      int i2 = __shfl_xor(bi, o, 64);
      if (v2 > bv || (v2 == bv && i2 < bi)) { bv = v2; bi = i2; }
    }
    bv = __shfl(bv, 0, 64);
    bi = __shfl(bi, 0, 64);
    if (l == 0) {
      out_vals[row * TOPK + pass] = bv;
      out_idx[row * TOPK + pass] = (float)bi;
    }
    lastV = bv;
    lastI = bi;
  }
}

// ---------------- gather retrieved = mem_n[topk_idx] -----------------------

__global__ __launch_bounds__(256) void gather_kernel(
    const float* __restrict__ out_idx, const float* __restrict__ mem,
    const float* __restrict__ invn, float* __restrict__ out_retr) {
  int p = blockIdx.x;
  int idx = (int)out_idx[p];
  float inv = invn[idx];
  int c = threadIdx.x * 4;
  float4 v = *(const float4*)(mem + (size_t)idx * D + c);
  v.x *= inv; v.y *= inv; v.z *= inv; v.w *= inv;
  *(float4*)(out_retr + (size_t)p * D + c) = v;
}

// ---------------- launch ---------------------------------------------------

extern "C" void kernel_launch(void* const* d_in, const int* in_sizes, int n_in,
                              void* d_out, int out_size, void* d_ws,
                              size_t ws_size, hipStream_t stream) {
  const float* query = (const float*)d_in[0];
  const float* W1 = (const float*)d_in[1];
  const float* b1 = (const float*)d_in[2];
  const float* ln_g = (const float*)d_in[3];
  const float* ln_b = (const float*)d_in[4];
  const float* W2 = (const float*)d_in[5];
  const float* b2 = (const float*)d_in[6];
  const float* mem = (const float*)d_in[7];

  float* out = (float*)d_out;
  float* out_refined = out;                    // 262144
  float* out_vals = out + 262144;              // 4096
  float* out_idx = out + 262144 + 4096;        // 4096
  float* out_retr = out + 262144 + 8192;       // 256*16*1024

  float* wsp = (float*)d_ws;
  float* invn = wsp;                           // 100352
  float* Qf = wsp + 100352;                    // 262144 (query frags, then Hf)
  float* Af = wsp + 362496;                    // 262144
  float* W1f = wsp + 624640;                   // 1048576
  float* W2f = wsp + 1673216;                  // 1048576
  float* part = wsp + 2721792;                 // 1048576
  float* cand_v = wsp + 3770368;               // 131072 (32 chunks max)
  int* cand_i = (int*)(wsp + 3901440);         // 131072
  int* ctrs = (int*)(wsp + 4032512);           // 64
  float* sims = wsp + 4032576;

  // chunking by available workspace
  long ws_floats = (long)(ws_size / 4);
  long avail = ws_floats - 4032640;
  int tpc = (int)(avail / 16384);
  if (tpc > NT_TOT) tpc = NT_TOT;
  if (tpc < 1) tpc = 1;
  int nchunk = (NT_TOT + tpc - 1) / tpc;
  if (nchunk > 32) nchunk = 32;
  tpc = (NT_TOT + nchunk - 1) / nchunk;
  int stride = tpc * 64;

  zero_ctrs_kernel<<<1, 64, 0, stream>>>(ctrs);
  prep_bf16_kernel<<<128, 256, 0, stream>>>(query, Qf, 16);
  prep_bf16_kernel<<<512, 256, 0, stream>>>(W1, W1f, 64);
  prep_bf16_kernel<<<512, 256, 0, stream>>>(W2, W2f, 64);
  mfma_gemm_kernel<<<256, 256, 0, stream>>>(Qf, W1f, part);
  reduce_ln_gelu_kernel<<<256, 256, 0, stream>>>(part, b1, ln_g, ln_b, Qf);
  mfma_gemm_kernel<<<256, 256, 0, stream>>>(Qf, W2f, part);
  reduce_l2norm_kernel<<<256, 256, 0, stream>>>(part, b2, out_refined, Af);
  for (int c = 0; c < nchunk; ++c) {
    int t0 = c * tpc;
    int nt = NT_TOT - t0;
    if (nt > tpc) nt = tpc;
    if (nt <= 0) break;
    int base = t0 * 64;
    sims_gemm_kernel<<<768, 256, 0, stream>>>(Af, mem, invn, ctrs + c, sims,
                                              nt, base, stride);
    int nvalid = NMEM - base;
    if (nvalid > nt * 64) nvalid = nt * 64;
    topk_chunk_kernel<<<256, 512, 0, stream>>>(sims, stride, base, nvalid,
                                               cand_v + c * 4096,
                                               cand_i + c * 4096);
  }
  final_merge_kernel<<<256, 64, 0, stream>>>(cand_v, cand_i, nchunk, out_vals,
                                             out_idx);
  gather_kernel<<<BQ * TOPK, 256, 0, stream>>>(out_idx, mem, invn, out_retr);
}

// Round 9
// 414.432 us; speedup vs baseline: 1.4058x; 1.0128x over previous
//
#include <hip/hip_runtime.h>
#include <float.h>
#include <math.h>

#define D 1024
#define BQ 256
#define NMEM 100000
#define TOPK 16
#define NT_TOT 1563   // 64-col tiles covering 100032 >= 100000

typedef __attribute__((ext_vector_type(4))) float f32x4;
typedef __attribute__((ext_vector_type(8))) short s16x8;

__device__ __forceinline__ void mfma16(f32x4& d, s16x8 a, s16x8 b) {
  asm("v_mfma_f32_16x16x32_bf16 %0, %1, %2, %0" : "+v"(d) : "v"(a), "v"(b));
}

__device__ __forceinline__ unsigned short bf16rtne(float x) {
  unsigned u = __float_as_uint(x);
  unsigned r = u + 0x7fffu + ((u >> 16) & 1u);
  return (unsigned short)(r >> 16);
}

__device__ __forceinline__ void cvt8(float4 a, float4 b, s16x8* hi, s16x8* lo,
                                     float* ssq) {
  float xs[8] = {a.x, a.y, a.z, a.w, b.x, b.y, b.z, b.w};
  union { s16x8 v; unsigned short u[8]; } H, L;
#pragma unroll
  for (int e = 0; e < 8; ++e) {
    float x = xs[e];
    unsigned short h = bf16rtne(x);
    float hf = __uint_as_float(((unsigned)h) << 16);
    H.u[e] = (short)h;
    L.u[e] = (short)bf16rtne(x - hf);
    *ssq = fmaf(x, x, *ssq);
  }
  *hi = H.v;
  *lo = L.v;
}

// ---------------- reductions ----------------

__device__ __forceinline__ float waveReduceSum(float v) {
#pragma unroll
  for (int o = 32; o > 0; o >>= 1) v += __shfl_xor(v, o, 64);
  return v;
}

__device__ __forceinline__ float blockReduceSum(float v, float* sbuf) {
  v = waveReduceSum(v);
  int w = threadIdx.x >> 6;
  if ((threadIdx.x & 63) == 0) sbuf[w] = v;
  __syncthreads();
  float r = sbuf[0] + sbuf[1] + sbuf[2] + sbuf[3];
  __syncthreads();
  return r;
}

// ---------------- prep: split [R][1024] f32 into bf16 hi/lo frag layout ----

__global__ __launch_bounds__(256) void prep_bf16_kernel(
    const float* __restrict__ src, float* __restrict__ dst, int R16) {
  int g = blockIdx.x * 256 + threadIdx.x;
  int l = g & 63;
  int mt = (g >> 6) % R16;
  int kb = (g >> 6) / R16;
  int row = mt * 16 + (l & 15);
  int k0 = kb * 32 + ((l >> 4) << 3);
  const float* s = src + (size_t)row * D + k0;
  float4 v0 = *(const float4*)s;
  float4 v1 = *(const float4*)(s + 4);
  float xs[8] = {v0.x, v0.y, v0.z, v0.w, v1.x, v1.y, v1.z, v1.w};
  union { uint4 q; unsigned short u[8]; } H, L;
#pragma unroll
  for (int e = 0; e < 8; ++e) {
    float x = xs[e];
    unsigned short h = bf16rtne(x);
    float hf = __uint_as_float(((unsigned)h) << 16);
    H.u[e] = h;
    L.u[e] = bf16rtne(x - hf);
  }
  char* db = (char*)dst + (size_t)kb * (R16 * 2048) + mt * 2048 + l * 16;
  *(uint4*)db = H.q;
  *(uint4*)(db + 1024) = L.q;
}

// ---------------- MFMA projection GEMM (K-chunked, bf16 single-acc) --------

__global__ __launch_bounds__(256) void mfma_gemm_kernel(
    const float* __restrict__ Afr, const float* __restrict__ Wfr,
    float* __restrict__ part) {
  int t = threadIdx.x;
  int w = t >> 6, l = t & 63;
  int ct = blockIdx.x & 63;
  int kc = blockIdx.x >> 6;
  f32x4 acc[4];
  f32x4 zz = {0.f, 0.f, 0.f, 0.f};
#pragma unroll
  for (int mi = 0; mi < 4; ++mi) acc[mi] = zz;
  const char* ab0 = (const char*)Afr + w * 8192 + l * 16;
  const char* bb0 = (const char*)Wfr + ct * 2048 + l * 16;
#pragma unroll 2
  for (int s = 0; s < 8; ++s) {
    int kb = kc * 8 + s;
    const char* bb = bb0 + (size_t)kb * 131072;
    s16x8 bh = *(const s16x8*)(bb);
    s16x8 bl = *(const s16x8*)(bb + 1024);
    const char* ab = ab0 + (size_t)kb * 32768;
#pragma unroll
    for (int mi = 0; mi < 4; ++mi) {
      s16x8 ah = *(const s16x8*)(ab + mi * 2048);
      s16x8 al = *(const s16x8*)(ab + mi * 2048 + 1024);
      mfma16(acc[mi], ah, bh);
      mfma16(acc[mi], ah, bl);
      mfma16(acc[mi], al, bh);
    }
  }
  float* pb = part + (size_t)kc * 262144 + ct * 16 + (l & 15);
#pragma unroll
  for (int mi = 0; mi < 4; ++mi)
#pragma unroll
    for (int j = 0; j < 4; ++j) {
      int row = w * 64 + mi * 16 + ((l >> 4) << 2) + j;
      pb[(size_t)row * 1024] = acc[mi][j];
    }
}

// ------- reduce partials + bias + LayerNorm + GELU -> Hf bf16 frags --------

__global__ __launch_bounds__(256) void reduce_ln_gelu_kernel(
    const float* __restrict__ part, const float* __restrict__ bias,
    const float* __restrict__ g, const float* __restrict__ b,
    float* __restrict__ Hf) {
  __shared__ float sbuf[4];
  int row = blockIdx.x, t = threadIdx.x;
  const float* p = part + (size_t)row * 1024 + t * 4;
  float4 x0 = *(const float4*)(p);
  float4 x1 = *(const float4*)(p + 262144);
  float4 x2 = *(const float4*)(p + 524288);
  float4 x3 = *(const float4*)(p + 786432);
  float4 bb = *(const float4*)(bias + t * 4);
  float vx = x0.x + x1.x + x2.x + x3.x + bb.x;
  float vy = x0.y + x1.y + x2.y + x3.y + bb.y;
  float vz = x0.z + x1.z + x2.z + x3.z + bb.z;
  float vw = x0.w + x1.w + x2.w + x3.w + bb.w;
  float s = blockReduceSum(vx + vy + vz + vw, sbuf);
  float mu = s * (1.0f / D);
  float dx = vx - mu, dy = vy - mu, dz = vz - mu, dw = vw - mu;
  float ss = blockReduceSum(dx * dx + dy * dy + dz * dz + dw * dw, sbuf);
  float rstd = rsqrtf(ss * (1.0f / D) + 1e-5f);
  float4 gg = *(const float4*)(g + t * 4);
  float4 be = *(const float4*)(b + t * 4);
  float y[4];
  y[0] = dx * rstd * gg.x + be.x;
  y[1] = dy * rstd * gg.y + be.y;
  y[2] = dz * rstd * gg.z + be.z;
  y[3] = dw * rstd * gg.w + be.w;
  const float c = 0.70710678118654752f;
  union { uint2 q; unsigned short u[4]; } H, L;
#pragma unroll
  for (int e = 0; e < 4; ++e) {
    float ye = 0.5f * y[e] * (1.0f + erff(y[e] * c));
    unsigned short h = bf16rtne(ye);
    float hf = __uint_as_float(((unsigned)h) << 16);
    H.u[e] = h;
    L.u[e] = bf16rtne(ye - hf);
  }
  int kb = t >> 3, oct = (t >> 1) & 3;
  char* db = (char*)Hf + (size_t)kb * 32768 + (row >> 4) * 2048 +
             ((row & 15) + oct * 16) * 16 + (t & 1) * 8;
  *(uint2*)db = H.q;
  *(uint2*)(db + 1024) = L.q;
}

// ------- reduce partials + bias + L2 norm -> out_refined + Af bf16 frags ---

__global__ __launch_bounds__(256) void reduce_l2norm_kernel(
    const float* __restrict__ part, const float* __restrict__ bias,
    float* __restrict__ outRef, float* __restrict__ Af) {
  __shared__ float sbuf[4];
  int row = blockIdx.x, t = threadIdx.x;
  const float* p = part + (size_t)row * 1024 + t * 4;
  float4 x0 = *(const float4*)(p);
  float4 x1 = *(const float4*)(p + 262144);
  float4 x2 = *(const float4*)(p + 524288);
  float4 x3 = *(const float4*)(p + 786432);
  float4 bb = *(const float4*)(bias + t * 4);
  float vx = x0.x + x1.x + x2.x + x3.x + bb.x;
  float vy = x0.y + x1.y + x2.y + x3.y + bb.y;
  float vz = x0.z + x1.z + x2.z + x3.z + bb.z;
  float vw = x0.w + x1.w + x2.w + x3.w + bb.w;
  float ss = blockReduceSum(vx * vx + vy * vy + vz * vz + vw * vw, sbuf);
  float inv = 1.0f / fmaxf(sqrtf(ss), 1e-12f);
  float y[4] = {vx * inv, vy * inv, vz * inv, vw * inv};
  *(float4*)(outRef + (size_t)row * D + t * 4) =
      make_float4(y[0], y[1], y[2], y[3]);
  union { uint2 q; unsigned short u[4]; } H, L;
#pragma unroll
  for (int e = 0; e < 4; ++e) {
    unsigned short h = bf16rtne(y[e]);
    float hf = __uint_as_float(((unsigned)h) << 16);
    H.u[e] = h;
    L.u[e] = bf16rtne(y[e] - hf);
  }
  int kb = t >> 3, oct = (t >> 1) & 3;
  char* db = (char*)Af + (size_t)kb * 32768 + (row >> 4) * 2048 +
             ((row & 15) + oct * 16) * 16 + (t & 1) * 8;
  *(uint2*)db = H.q;
  *(uint2*)(db + 1024) = L.q;
}

__global__ void zero_ctrs_kernel(int* c) { c[threadIdx.x] = 0; }

// ---------------- sims GEMM: 256x64 tiles, B-only LDS, reg-prefetched A ----
// SAFETY MODEL (R6-R8 lessons): NO manual vmcnt anywhere. Every global load
// is a plain C++ load into registers (compiler's post-RA waitcnt pass guards
// each use precisely). LDS holds only B (double-buffered) -> the per-step
// barrier needs only lgkmcnt(0). A-fragments are wave-private, prefetched
// one step ahead into a rotating register set from the L2-resident Af.
// braw rotates over 3 sets (2-step HBM lead).

#define SBODY(J, BP, ACh, ACl, ANh, ANl, RC0, RC1, RP0, RP1, DOPFB, DOPFA,    \
              DOCONV)                                                          \
  do {                                                                         \
    if (DOCONV) {                                                              \
      s16x8 bhn_, bln_;                                                        \
      cvt8(RC0, RC1, &bhn_, &bln_, &ssq);                                      \
      char* bw_ = smem + (1 - (BP)) * 8192 + bwoff;                            \
      *(s16x8*)bw_ = bhn_;                                                     \
      *(s16x8*)(bw_ + 1024) = bln_;                                            \
    }                                                                          \
    if (DOPFA) {                                                               \
      const char* an_ = afbytes + (size_t)((J) + 1) * 32768 + w4x + l * 16;    \
      _Pragma("unroll") for (int mi = 0; mi < 4; ++mi) {                       \
        ANh[mi] = *(const s16x8*)(an_ + mi * 2048);                            \
        ANl[mi] = *(const s16x8*)(an_ + mi * 2048 + 1024);                     \
      }                                                                        \
    }                                                                          \
    if (DOPFB) {                                                               \
      const float* p_ = bsrc + ((J) + 3) * 32;                                 \
      RP0 = *(const float4*)p_;                                                \
      RP1 = *(const float4*)(p_ + 4);                                          \
    }                                                                          \
    __builtin_amdgcn_s_setprio(1);                                             \
    _Pragma("unroll") for (int ni = 0; ni < 4; ++ni) {                         \
      const char* bb_ = smem + (BP)*8192 + ni * 2048 + l * 16;                 \
      s16x8 bh_ = *(const s16x8*)bb_;                                          \
      s16x8 bl_ = *(const s16x8*)(bb_ + 1024);                                 \
      _Pragma("unroll") for (int mi = 0; mi < 4; ++mi) {                       \
        mfma16(acc[mi][ni], ACh[mi], bh_);                                     \
        mfma16(acc[mi][ni], ACh[mi], bl_);                                     \
        mfma16(acc[mi][ni], ACl[mi], bh_);                                     \
      }                                                                        \
    }                                                                          \
    __builtin_amdgcn_s_setprio(0);                                             \
    asm volatile("s_waitcnt lgkmcnt(0)\n\ts_barrier" ::: "memory");            \
    __builtin_amdgcn_sched_barrier(0);                                         \
  } while (0)

__global__ __launch_bounds__(256, 2) void sims_gemm_kernel(
    const float* __restrict__ Afrag, const float* __restrict__ mem,
    float* __restrict__ invn, int* __restrict__ ctr,
    float* __restrict__ simsbuf, int ntiles, int chunk_n0, int stride_cols) {
  __shared__ __align__(16) char smem[16384];  // bufB[2] only
  __shared__ float sInvF[64];
  __shared__ int s_tile;
  const int t = threadIdx.x;
  const int w = t >> 6, l = t & 63;
  const int w4x = (w * 4) * 2048;
  // B roles (R5-proven): row t>>2 of tile, k-octet t&3
  const int brow_loc = t >> 2;
  const int kseg = t & 3;
  const int bwoff = (brow_loc >> 4) * 2048 + ((brow_loc & 15) + kseg * 16) * 16;
  const char* afbytes = (const char*)Afrag;

  while (true) {
    if (t == 0) s_tile = atomicAdd(ctr, 1);
    __syncthreads();
    const int unit = s_tile;
    __syncthreads();
    if (unit >= ntiles) break;
    const int n0 = chunk_n0 + unit * 64;
    const int brow = min(n0 + brow_loc, NMEM - 1);
    const float* bsrc = mem + (size_t)brow * D + kseg * 8;

    f32x4 acc[4][4];
    f32x4 zz = {0.f, 0.f, 0.f, 0.f};
#pragma unroll
    for (int mi = 0; mi < 4; ++mi)
#pragma unroll
      for (int ni = 0; ni < 4; ++ni) acc[mi][ni] = zz;
    float ssq = 0.f;

    // register sets: braw R0..R2 (each 2 float4), A-frags S0,S1 (each 8 s16x8)
    float4 r0a, r0b, r1a, r1b, r2a, r2b;
    s16x8 s0h[4], s0l[4], s1h[4], s1l[4];

    // ---- prologue: braw0..2 + A(0) loads (plain), conv(0)->bufB0, barrier
    r0a = *(const float4*)bsrc;
    r0b = *(const float4*)(bsrc + 4);
    r1a = *(const float4*)(bsrc + 32);
    r1b = *(const float4*)(bsrc + 36);
    r2a = *(const float4*)(bsrc + 64);
    r2b = *(const float4*)(bsrc + 68);
    {
      const char* a0_ = afbytes + w4x + l * 16;
#pragma unroll
      for (int mi = 0; mi < 4; ++mi) {
        s0h[mi] = *(const s16x8*)(a0_ + mi * 2048);
        s0l[mi] = *(const s16x8*)(a0_ + mi * 2048 + 1024);
      }
    }
    {
      s16x8 bh0, bl0;
      cvt8(r0a, r0b, &bh0, &bl0, &ssq);
      *(s16x8*)(smem + bwoff) = bh0;
      *(s16x8*)(smem + bwoff + 1024) = bl0;
    }
    asm volatile("s_waitcnt lgkmcnt(0)\n\ts_barrier" ::: "memory");
    __builtin_amdgcn_sched_barrier(0);

    // ---- steps 0..23 (mod-6 schedule)
#pragma unroll 1
    for (int jb = 0; jb < 24; jb += 6) {
      SBODY(jb + 0, 0, s0h, s0l, s1h, s1l, r1a, r1b, r0a, r0b, 1, 1, 1);
      SBODY(jb + 1, 1, s1h, s1l, s0h, s0l, r2a, r2b, r1a, r1b, 1, 1, 1);
      SBODY(jb + 2, 0, s0h, s0l, s1h, s1l, r0a, r0b, r2a, r2b, 1, 1, 1);
      SBODY(jb + 3, 1, s1h, s1l, s0h, s0l, r1a, r1b, r0a, r0b, 1, 1, 1);
      SBODY(jb + 4, 0, s0h, s0l, s1h, s1l, r2a, r2b, r1a, r1b, 1, 1, 1);
      SBODY(jb + 5, 1, s1h, s1l, s0h, s0l, r0a, r0b, r2a, r2b, 1, 1, 1);
    }
    // ---- steps 24..29 (last braw prefetch at J=28 -> braw31)
    SBODY(24, 0, s0h, s0l, s1h, s1l, r1a, r1b, r0a, r0b, 1, 1, 1);
    SBODY(25, 1, s1h, s1l, s0h, s0l, r2a, r2b, r1a, r1b, 1, 1, 1);
    SBODY(26, 0, s0h, s0l, s1h, s1l, r0a, r0b, r2a, r2b, 1, 1, 1);
    SBODY(27, 1, s1h, s1l, s0h, s0l, r1a, r1b, r0a, r0b, 1, 1, 1);
    SBODY(28, 0, s0h, s0l, s1h, s1l, r2a, r2b, r1a, r1b, 1, 1, 1);
    SBODY(29, 1, s1h, s1l, s0h, s0l, r0a, r0b, r2a, r2b, 0, 1, 1);
    // ---- step 30: conv braw31 (r1), prefetch A31; step 31: compute only
    SBODY(30, 0, s0h, s0l, s1h, s1l, r1a, r1b, r0a, r0b, 0, 1, 1);
    SBODY(31, 1, s1h, s1l, s0h, s0l, r2a, r2b, r1a, r1b, 0, 0, 0);

    // ---- epilogue: col norms via shfl (octet lanes t^1,t^2), scaled store
    float s2 = ssq + __shfl_xor(ssq, 1, 64);
    s2 = s2 + __shfl_xor(s2, 2, 64);
    float inv = 1.0f / fmaxf(sqrtf(s2), 1e-12f);
    if (kseg == 0) {
      sInvF[brow_loc] = inv;
      int col = n0 + brow_loc;
      if (col < NMEM) invn[col] = inv;
    }
    __syncthreads();
    float siv[4];
#pragma unroll
    for (int ni = 0; ni < 4; ++ni) siv[ni] = sInvF[ni * 16 + (l & 15)];
    float* srow = simsbuf + (size_t)(unit * 64);
#pragma unroll
    for (int mi = 0; mi < 4; ++mi)
#pragma unroll
      for (int jj = 0; jj < 4; ++jj) {
        int row = w * 64 + mi * 16 + ((l >> 4) << 2) + jj;
        float* rp = srow + (size_t)row * stride_cols;
#pragma unroll
        for (int ni = 0; ni < 4; ++ni)
          rp[ni * 16 + (l & 15)] = acc[mi][ni][jj] * siv[ni];
      }
    __syncthreads();  // sInvF reads done before next tile overwrites
  }
}

// ---------------- per-chunk top-16 scan over scaled sims -------------------

__global__ __launch_bounds__(512) void topk_chunk_kernel(
    const float* __restrict__ simsbuf, int stride_cols, int chunk_n0,
    int nvalid, float* __restrict__ cv, int* __restrict__ ci) {
  __shared__ float wvv[8];
  __shared__ int wii[8];
  __shared__ float sbv;
  __shared__ int sbi;
  int row = blockIdx.x, t = threadIdx.x;
  const float* S = simsbuf + (size_t)row * stride_cols;
  float tv[16];
  int ti[16];
#pragma unroll
  for (int s = 0; s < 16; ++s) { tv[s] = -FLT_MAX; ti[s] = 2147483647; }
  float curMin = -FLT_MAX;
  for (int c0 = t * 4; c0 < nvalid; c0 += 2048) {
    float vv[4] = {-FLT_MAX, -FLT_MAX, -FLT_MAX, -FLT_MAX};
    if (c0 + 4 <= nvalid) {
      float4 v = *(const float4*)(S + c0);
      vv[0] = v.x; vv[1] = v.y; vv[2] = v.z; vv[3] = v.w;
    } else {
#pragma unroll
      for (int e = 0; e < 4; ++e)
        if (c0 + e < nvalid) vv[e] = S[c0 + e];
    }
#pragma unroll
    for (int e = 0; e < 4; ++e) {
      float v = vv[e];
      if (v > curMin) {
        int n = chunk_n0 + c0 + e;
        int ms = 0;
        float mv = tv[0];
#pragma unroll
        for (int s = 1; s < 16; ++s)
          if (tv[s] < mv) { mv = tv[s]; ms = s; }
#pragma unroll
        for (int s = 0; s < 16; ++s)
          if (s == ms) { tv[s] = v; ti[s] = n; }
        curMin = tv[0];
#pragma unroll
        for (int s = 1; s < 16; ++s) curMin = fminf(curMin, tv[s]);
      }
    }
  }
  float lastV = FLT_MAX;
  int lastI = -1;
  for (int pass = 0; pass < TOPK; ++pass) {
    float bv = -FLT_MAX;
    int bi = 2147483647;
#pragma unroll
    for (int s = 0; s < 16; ++s) {
      float v = tv[s];
      int idx = ti[s];
      bool qual = (v < lastV) || (v == lastV && idx > lastI);
      bool bet = (v > bv) || (v == bv && idx < bi);
      if (qual && bet) { bv = v; bi = idx; }
    }
#pragma unroll
    for (int o = 32; o > 0; o >>= 1) {
      float v2 = __shfl_xor(bv, o, 64);
      int i2 = __shfl_xor(bi, o, 64);
      if (v2 > bv || (v2 == bv && i2 < bi)) { bv = v2; bi = i2; }
    }
    if ((t & 63) == 0) { wvv[t >> 6] = bv; wii[t >> 6] = bi; }
    __syncthreads();
    if (t == 0) {
      float fv = wvv[0];
      int fi = wii[0];
#pragma unroll
      for (int u = 1; u < 8; ++u) {
        if (wvv[u] > fv || (wvv[u] == fv && wii[u] < fi)) {
          fv = wvv[u];
          fi = wii[u];
        }
      }
      sbv = fv;
      sbi = fi;
      cv[row * TOPK + pass] = fv;
      ci[row * TOPK + pass] = fi;
    }
    __syncthreads();
    lastV = sbv;
    lastI = sbi;
  }
}

// ---------------- final merge across chunks --------------------------------

__global__ __launch_bounds__(64) void final_merge_kernel(
    const float* __restrict__ cand_v, const int* __restrict__ cand_i,
    int nchunk, float* __restrict__ out_vals, float* __restrict__ out_idx) {
  int row = blockIdx.x, l = threadIdx.x;
  int nc = nchunk * TOPK;
  float mv[8];
  int mi_[8];
#pragma unroll
  for (int u = 0; u < 8; ++u) {
    int p = l + u * 64;
    if (p < nc) {
      int ch = p >> 4;
      mv[u] = cand_v[ch * 4096 + row * TOPK + (p & 15)];
      mi_[u] = cand_i[ch * 4096 + row * TOPK + (p & 15)];
    } else {
      mv[u] = -FLT_MAX;
      mi_[u] = 2147483647;
    }
  }
  float lastV = FLT_MAX;
  int lastI = -1;
  for (int pass = 0; pass < TOPK; ++pass) {
    float bv = -FLT_MAX;
    int bi = 2147483647;
#pragma unroll
    for (int u = 0; u < 8; ++u) {
      bool qual = (mv[u] < lastV) || (mv[u] == lastV && mi_[u] > lastI);
      bool bet = (mv[u] > bv) || (mv[u] == bv && mi_[u] < bi);
      if (qual && bet) { bv = mv[u]; bi = mi_[u]; }
    }
#pragma unroll
    for (int o = 32; o > 0; o >>= 1) {
      float v2 = __shfl_xor(bv, o, 64);
      int i2 = __shfl_xor(bi, o, 64);
      if (v2 > bv || (v2 == bv && i2 < bi)) { bv = v2; bi = i2; }
    }
    bv = __shfl(bv, 0, 64);
    bi = __shfl(bi, 0, 64);
    if (l == 0) {
      out_vals[row * TOPK + pass] = bv;
      out_idx[row * TOPK + pass] = (float)bi;
    }
    lastV = bv;
    lastI = bi;
  }
}

// ---------------- gather retrieved = mem_n[topk_idx] -----------------------

__global__ __launch_bounds__(256) void gather_kernel(
    const float* __restrict__ out_idx, const float* __restrict__ mem,
    const float* __restrict__ invn, float* __restrict__ out_retr) {
  int p = blockIdx.x;
  int idx = (int)out_idx[p];
  float inv = invn[idx];
  int c = threadIdx.x * 4;
  float4 v = *(const float4*)(mem + (size_t)idx * D + c);
  v.x *= inv; v.y *= inv; v.z *= inv; v.w *= inv;
  *(float4*)(out_retr + (size_t)p * D + c) = v;
}

// ---------------- launch ---------------------------------------------------

extern "C" void kernel_launch(void* const* d_in, const int* in_sizes, int n_in,
                              void* d_out, int out_size, void* d_ws,
                              size_t ws_size, hipStream_t stream) {
  const float* query = (const float*)d_in[0];
  const float* W1 = (const float*)d_in[1];
  const float* b1 = (const float*)d_in[2];
  const float* ln_g = (const float*)d_in[3];
  const float* ln_b = (const float*)d_in[4];
  const float* W2 = (const float*)d_in[5];
  const float* b2 = (const float*)d_in[6];
  const float* mem = (const float*)d_in[7];

  float* out = (float*)d_out;
  float* out_refined = out;                    // 262144
  float* out_vals = out + 262144;              // 4096
  float* out_idx = out + 262144 + 4096;        // 4096
  float* out_retr = out + 262144 + 8192;       // 256*16*1024

  float* wsp = (float*)d_ws;
  float* invn = wsp;                           // 100352
  float* Qf = wsp + 100352;                    // 262144 (query frags, then Hf)
  float* Af = wsp + 362496;                    // 262144
  float* W1f = wsp + 624640;                   // 1048576
  float* W2f = wsp + 1673216;                  // 1048576
  float* part = wsp + 2721792;                 // 1048576
  float* cand_v = wsp + 3770368;               // 131072 (32 chunks max)
  int* cand_i = (int*)(wsp + 3901440);         // 131072
  int* ctrs = (int*)(wsp + 4032512);           // 64
  float* sims = wsp + 4032576;

  long ws_floats = (long)(ws_size / 4);
  long avail = ws_floats - 4032640;
  int tpc = (int)(avail / 16384);
  if (tpc > NT_TOT) tpc = NT_TOT;
  if (tpc < 1) tpc = 1;
  int nchunk = (NT_TOT + tpc - 1) / tpc;
  if (nchunk > 32) nchunk = 32;
  tpc = (NT_TOT + nchunk - 1) / nchunk;
  int stride = tpc * 64;

  zero_ctrs_kernel<<<1, 64, 0, stream>>>(ctrs);
  prep_bf16_kernel<<<128, 256, 0, stream>>>(query, Qf, 16);
  prep_bf16_kernel<<<512, 256, 0, stream>>>(W1, W1f, 64);
  prep_bf16_kernel<<<512, 256, 0, stream>>>(W2, W2f, 64);
  mfma_gemm_kernel<<<256, 256, 0, stream>>>(Qf, W1f, part);
  reduce_ln_gelu_kernel<<<256, 256, 0, stream>>>(part, b1, ln_g, ln_b, Qf);
  mfma_gemm_kernel<<<256, 256, 0, stream>>>(Qf, W2f, part);
  reduce_l2norm_kernel<<<256, 256, 0, stream>>>(part, b2, out_refined, Af);
  for (int c = 0; c < nchunk; ++c) {
    int t0 = c * tpc;
    int nt = NT_TOT - t0;
    if (nt > tpc) nt = tpc;
    if (nt <= 0) break;
    int base = t0 * 64;
    sims_gemm_kernel<<<512, 256, 0, stream>>>(Af, mem, invn, ctrs + c, sims,
                                              nt, base, stride);
    int nvalid = NMEM - base;
    if (nvalid > nt * 64) nvalid = nt * 64;
    topk_chunk_kernel<<<256, 512, 0, stream>>>(sims, stride, base, nvalid,
                                               cand_v + c * 4096,
                                               cand_i + c * 4096);
  }
  final_merge_kernel<<<256, 64, 0, stream>>>(cand_v, cand_i, nchunk, out_vals,
                                             out_idx);
  gather_kernel<<<BQ * TOPK, 256, 0, stream>>>(out_idx, mem, invn, out_retr);
}